// Round 3
// baseline (689.443 us; speedup 1.0000x reference)
//
#include <hip/hip_runtime.h>
#include <hip/hip_bf16.h>
#include <stdint.h>

// Problem constants
#define M_TOT 4096   // 2 * 2048
#define K_DIM 4096   // IN_FEATURES
#define N_DIM 16384  // OUT_FEATURES

typedef __attribute__((ext_vector_type(8))) short bf16x8;  // 8 bf16 = 4 VGPRs
typedef __attribute__((ext_vector_type(4))) float f32x4;   // MFMA 16x16 acc

__device__ __forceinline__ unsigned short f2bf(float f) {
  union { float f; unsigned u; } v; v.f = f;
  unsigned r = v.u + 0x7fffu + ((v.u >> 16) & 1u);  // RNE
  return (unsigned short)(r >> 16);
}

__global__ void cvt_f32_bf16_k(const float4* __restrict__ src,
                               ushort4* __restrict__ dst, int n4) {
  int stride = gridDim.x * blockDim.x;
  for (int i = blockIdx.x * blockDim.x + threadIdx.x; i < n4; i += stride) {
    float4 v = src[i];
    ushort4 o;
    o.x = f2bf(v.x); o.y = f2bf(v.y); o.z = f2bf(v.z); o.w = f2bf(v.w);
    dst[i] = o;
  }
}

__global__ void cvt_i32_bf16_k(const int4* __restrict__ src,
                               ushort4* __restrict__ dst, int n4) {
  int stride = gridDim.x * blockDim.x;
  for (int i = blockIdx.x * blockDim.x + threadIdx.x; i < n4; i += stride) {
    int4 v = src[i];
    ushort4 o;
    o.x = f2bf((float)v.x); o.y = f2bf((float)v.y);
    o.z = f2bf((float)v.z); o.w = f2bf((float)v.w);
    dst[i] = o;
  }
}

__device__ __forceinline__ void gload16(const void* g, void* l) {
  __builtin_amdgcn_global_load_lds(
      (__attribute__((address_space(1))) void*)(g),
      (__attribute__((address_space(3))) void*)(l),
      16, 0, 0);
}

// XOR-swizzle involution on byte offsets within a 16KB block ([256][32] bf16,
// 64B rows). XORs bits 4-6 with bits 7-9: bits 7-9 untouched -> involution.
// Verified round 2: SQ_LDS_BANK_CONFLICT == 0.
#define SWZ(o) ((o) ^ ((((o) >> 7) & 7) << 4))

#define MFMA_B16(a, b, c) __builtin_amdgcn_mfma_f32_16x16x32_bf16(a, b, c, 0, 0, 0)

// 256x256 tile, BK=64, 8 waves (2M x 4N), 4 phases/K-tile, counted vmcnt(4),
// setprio around MFMA, XOR-swizzled LDS, register-pipelined fragment reads
// (P2/P3/P4 fragments loaded during the previous phase's tail).
// LDS (bytes): buf b at b*65536; A slice s at +s*16384; B slice s at +32768+s*16384.
__global__ __launch_bounds__(512, 2)
void gemm_8phase(const ushort* __restrict__ A, const ushort* __restrict__ W,
                 const float* __restrict__ scale, const float* __restrict__ bias,
                 float* __restrict__ C) {
  __shared__ __align__(16) ushort lds[65536];  // 128 KiB
  char* lbase = (char*)lds;

  const int tid  = threadIdx.x;
  const int lane = tid & 63;
  const int wave = tid >> 6;
  const int wm   = wave >> 2;  // 0..1
  const int wn   = wave & 3;   // 0..3
  const int r    = lane & 15;
  const int kq16 = (lane >> 4) << 4;  // kq*16 bytes

  // XCD column-chunked mapping: bid%8 = XCD; each XCD owns tn in [8*xcd, 8*xcd+8),
  // tm fastest -> 16 consecutive same-XCD blocks share one B panel (L2-resident).
  const int bid = blockIdx.x;
  const int xcd = bid & 7;
  const int ic  = bid >> 3;                 // 0..127 within XCD chunk
  const int tn  = (xcd << 3) | (ic >> 4);   // 0..63
  const int tm  = ic & 15;                  // 0..15
  const int row0 = tm * 256;
  const int col0 = tn * 256;

  // Staging: per-thread global coords; linear LDS dest off holds logical SWZ(off).
  int s_row0, s_col0, s_row1, s_col1;
  {
    int l0 = SWZ(tid * 16);
    int l1 = SWZ(8192 + tid * 16);
    s_row0 = l0 >> 6; s_col0 = (l0 & 63) >> 1;
    s_row1 = l1 >> 6; s_col1 = (l1 & 63) >> 1;
  }

  auto STAGE = [&](const ushort* G, int rb, int kb, int blkB) {
    gload16(G + (size_t)(rb + s_row0) * K_DIM + kb + s_col0,
            lbase + blkB + (wave << 10));
    gload16(G + (size_t)(rb + s_row1) * K_DIM + kb + s_col1,
            lbase + blkB + 8192 + (wave << 10));
  };

  f32x4 acc[8][4];
#pragma unroll
  for (int i = 0; i < 8; ++i)
#pragma unroll
    for (int j = 0; j < 4; ++j)
      acc[i][j] = (f32x4){0.f, 0.f, 0.f, 0.f};

  // Prologue: T0 all 4 blocks + T1 slice-0 blocks
  STAGE(A, row0, 0,  0);
  STAGE(W, col0, 0,  32768);
  STAGE(A, row0, 32, 16384);
  STAGE(W, col0, 32, 49152);
  STAGE(A, row0, 64, 65536);
  STAGE(W, col0, 64, 98304);
  asm volatile("s_waitcnt vmcnt(4)" ::: "memory");  // T0 resident, T1-s0 in flight
  __builtin_amdgcn_s_barrier();

  bf16x8 aE[4], aO[4], bA[4], bB[4];

  for (int t = 0; t < 64; ++t) {
    const int cur  = t & 1;
    const int curB = cur << 16;
    const int nxtB = (cur ^ 1) << 16;
    const int t1   = (t + 1 < 64) ? t + 1 : 63;  // clamp keeps vmcnt uniform
    const int t2   = (t + 2 < 64) ? t + 2 : 63;

    // ---- P1: ks0 x m-half0 (self-loading: data only barrier-certified now) ----
#pragma unroll
    for (int q = 0; q < 4; ++q)
      aE[q] = *(const bf16x8*)(lbase + curB + SWZ(((wm * 128 + q * 16 + r) << 6) + kq16));
#pragma unroll
    for (int q = 0; q < 4; ++q)
      bA[q] = *(const bf16x8*)(lbase + curB + 32768 + SWZ(((wn * 64 + q * 16 + r) << 6) + kq16));
    STAGE(A, row0, t1 * 64 + 32, nxtB + 16384);  // T(t+1) A s1
    __builtin_amdgcn_s_barrier();
    __builtin_amdgcn_s_setprio(1);
#pragma unroll
    for (int mi = 0; mi < 4; ++mi)
#pragma unroll
      for (int ni = 0; ni < 4; ++ni)
        acc[mi][ni] = MFMA_B16(aE[mi], bA[ni], acc[mi][ni]);
    __builtin_amdgcn_s_setprio(0);
    // prefetch P2 fragments (ks0 resident)
#pragma unroll
    for (int q = 0; q < 4; ++q)
      aO[q] = *(const bf16x8*)(lbase + curB + SWZ(((wm * 128 + (4 + q) * 16 + r) << 6) + kq16));
    __builtin_amdgcn_s_barrier();

    // ---- P2: ks0 x m-half1 ----
    STAGE(W, col0, t1 * 64 + 32, nxtB + 49152);  // T(t+1) B s1
    __builtin_amdgcn_s_barrier();
    __builtin_amdgcn_s_setprio(1);
#pragma unroll
    for (int mi = 0; mi < 4; ++mi)
#pragma unroll
      for (int ni = 0; ni < 4; ++ni)
        acc[4 + mi][ni] = MFMA_B16(aO[mi], bA[ni], acc[4 + mi][ni]);
    __builtin_amdgcn_s_setprio(0);
    // prefetch P3 fragments (ks1 resident since tile start)
#pragma unroll
    for (int q = 0; q < 4; ++q)
      aE[q] = *(const bf16x8*)(lbase + curB + 16384 + SWZ(((wm * 128 + q * 16 + r) << 6) + kq16));
#pragma unroll
    for (int q = 0; q < 4; ++q)
      bB[q] = *(const bf16x8*)(lbase + curB + 49152 + SWZ(((wn * 64 + q * 16 + r) << 6) + kq16));
    __builtin_amdgcn_s_barrier();

    // ---- P3: ks1 x m-half0 ----
    STAGE(A, row0, t2 * 64, curB);  // T(t+2) A s0 -> dead region
    __builtin_amdgcn_s_barrier();
    __builtin_amdgcn_s_setprio(1);
#pragma unroll
    for (int mi = 0; mi < 4; ++mi)
#pragma unroll
      for (int ni = 0; ni < 4; ++ni)
        acc[mi][ni] = MFMA_B16(aE[mi], bB[ni], acc[mi][ni]);
    __builtin_amdgcn_s_setprio(0);
    // prefetch P4 fragments
#pragma unroll
    for (int q = 0; q < 4; ++q)
      aO[q] = *(const bf16x8*)(lbase + curB + 16384 + SWZ(((wm * 128 + (4 + q) * 16 + r) << 6) + kq16));
    __builtin_amdgcn_s_barrier();

    // ---- P4: ks1 x m-half1 ----
    STAGE(W, col0, t2 * 64, curB + 32768);  // T(t+2) B s0 -> dead region
    __builtin_amdgcn_s_barrier();
    __builtin_amdgcn_s_setprio(1);
#pragma unroll
    for (int mi = 0; mi < 4; ++mi)
#pragma unroll
      for (int ni = 0; ni < 4; ++ni)
        acc[4 + mi][ni] = MFMA_B16(aO[mi], bB[ni], acc[4 + mi][ni]);
    __builtin_amdgcn_s_setprio(0);
    // counted wait: <=4 outstanding (= T(t+2) s0); T(t+1) s1 fully landed
    asm volatile("s_waitcnt vmcnt(4)" ::: "memory");
    __builtin_amdgcn_s_barrier();
  }

  // don't retire with in-flight LDS writes
  asm volatile("s_waitcnt vmcnt(0)" ::: "memory");

  // Epilogue: C/D layout col=lane&15, row=(lane>>4)*4+reg (verified rounds 1-2)
  const int kq = kq16 >> 4;
#pragma unroll
  for (int ni = 0; ni < 4; ++ni) {
    const int col = col0 + wn * 64 + ni * 16 + r;
    const float sc = scale[col];
    const float bv = bias[col];
#pragma unroll
    for (int mi = 0; mi < 8; ++mi) {
      const int rowb = row0 + wm * 128 + mi * 16 + kq * 4;
#pragma unroll
      for (int q = 0; q < 4; ++q)
        C[(size_t)(rowb + q) * N_DIM + col] = acc[mi][ni][q] * sc + bv;
    }
  }
}

extern "C" void kernel_launch(void* const* d_in, const int* in_sizes, int n_in,
                              void* d_out, int out_size, void* d_ws, size_t ws_size,
                              hipStream_t stream) {
  const float* x      = (const float*)d_in[0];
  const int*   wq     = (const int*)d_in[1];
  const float* wscale = (const float*)d_in[2];
  const float* wbias  = (const float*)d_in[3];
  float* out = (float*)d_out;

  const size_t xb_bytes = (size_t)M_TOT * K_DIM * 2;   // 32 MB
  const size_t wb_bytes = (size_t)N_DIM * K_DIM * 2;   // 128 MB
  if (ws_size < xb_bytes + wb_bytes) return;

  ushort* xb = (ushort*)d_ws;
  ushort* wb = (ushort*)((char*)d_ws + xb_bytes);

  cvt_f32_bf16_k<<<2048, 256, 0, stream>>>((const float4*)x, (ushort4*)xb,
                                           (M_TOT * K_DIM) / 4);
  cvt_i32_bf16_k<<<2048, 256, 0, stream>>>((const int4*)wq, (ushort4*)wb,
                                           (N_DIM * K_DIM) / 4);

  const int grid = (M_TOT / 256) * (N_DIM / 256);  // 16 * 64 = 1024
  gemm_8phase<<<grid, 512, 0, stream>>>(xb, wb, wscale, wbias, out);
}

// Round 4
// 678.794 us; speedup vs baseline: 1.0157x; 1.0157x over previous
//
#include <hip/hip_runtime.h>
#include <hip/hip_bf16.h>
#include <stdint.h>

// Problem constants
#define M_TOT 4096   // 2 * 2048
#define K_DIM 4096   // IN_FEATURES
#define N_DIM 16384  // OUT_FEATURES

typedef __attribute__((ext_vector_type(8))) short bf16x8;   // 8 bf16 = 4 VGPRs
typedef __attribute__((ext_vector_type(16))) float f32x16;  // MFMA 32x32 acc

__device__ __forceinline__ unsigned short f2bf(float f) {
  union { float f; unsigned u; } v; v.f = f;
  unsigned r = v.u + 0x7fffu + ((v.u >> 16) & 1u);  // RNE
  return (unsigned short)(r >> 16);
}

__global__ void cvt_f32_bf16_k(const float4* __restrict__ src,
                               ushort4* __restrict__ dst, int n4) {
  int stride = gridDim.x * blockDim.x;
  for (int i = blockIdx.x * blockDim.x + threadIdx.x; i < n4; i += stride) {
    float4 v = src[i];
    ushort4 o;
    o.x = f2bf(v.x); o.y = f2bf(v.y); o.z = f2bf(v.z); o.w = f2bf(v.w);
    dst[i] = o;
  }
}

__global__ void cvt_i32_bf16_k(const int4* __restrict__ src,
                               ushort4* __restrict__ dst, int n4) {
  int stride = gridDim.x * blockDim.x;
  for (int i = blockIdx.x * blockDim.x + threadIdx.x; i < n4; i += stride) {
    int4 v = src[i];
    ushort4 o;
    o.x = f2bf((float)v.x); o.y = f2bf((float)v.y);
    o.z = f2bf((float)v.z); o.w = f2bf((float)v.w);
    dst[i] = o;
  }
}

__device__ __forceinline__ void gload16(const void* g, void* l) {
  __builtin_amdgcn_global_load_lds(
      (__attribute__((address_space(1))) void*)(g),
      (__attribute__((address_space(3))) void*)(l),
      16, 0, 0);
}

// XOR-swizzle involution on byte offsets within a 16KB block ([256][32] bf16,
// 64B rows). XORs bits 4-6 with bits 7-9: bits 7-9 untouched -> involution.
// Verified round 2/3: SQ_LDS_BANK_CONFLICT == 0. Per-quarter-wave analysis holds
// for the 32-row fragment pattern too (rows 0-15 / 16-31 each spread 8 slots).
#define SWZ(o) ((o) ^ ((((o) >> 7) & 7) << 4))

#define MFMA32(a, b, c) __builtin_amdgcn_mfma_f32_32x32x16_bf16(a, b, c, 0, 0, 0)

// 256x256 tile, BK=64, 8 waves (2M x 4N), wave tile 128x64 as 4x2 frags of 32x32,
// 4 phases/K-tile (= 8 phases / 2 K-tiles), counted vmcnt(4), setprio, XOR-swizzle.
// LDS (bytes): buf b at b*65536; A slice s at +s*16384; B slice s at +32768+s*16384.
__global__ __launch_bounds__(512, 2)
void gemm_8phase(const ushort* __restrict__ A, const ushort* __restrict__ W,
                 const float* __restrict__ scale, const float* __restrict__ bias,
                 float* __restrict__ C) {
  __shared__ __align__(16) ushort lds[65536];  // 128 KiB
  char* lbase = (char*)lds;

  const int tid  = threadIdx.x;
  const int lane = tid & 63;
  const int wave = tid >> 6;
  const int wm   = wave >> 2;  // 0..1
  const int wn   = wave & 3;   // 0..3
  const int r32  = lane & 31;          // fragment row/col
  const int hk   = (lane >> 5) << 4;   // k-half byte offset (0 or 16)

  // XCD column-chunked mapping (round-3, verified: FETCH halved): bid%8 = XCD,
  // each XCD owns 8 tn columns, tm fastest -> B panel L2-resident per XCD.
  const int bid = blockIdx.x;
  const int xcd = bid & 7;
  const int ic  = bid >> 3;                 // 0..127
  const int tn  = (xcd << 3) | (ic >> 4);   // 0..63
  const int tm  = ic & 15;                  // 0..15
  const int row0 = tm * 256;
  const int col0 = tn * 256;

  // Staging: per-thread global coords; linear LDS dest off holds logical SWZ(off).
  int s_row0, s_col0, s_row1, s_col1;
  {
    int l0 = SWZ(tid * 16);
    int l1 = SWZ(8192 + tid * 16);
    s_row0 = l0 >> 6; s_col0 = (l0 & 63) >> 1;
    s_row1 = l1 >> 6; s_col1 = (l1 & 63) >> 1;
  }

  auto STAGE = [&](const ushort* G, int rb, int kb, int blkB) {
    gload16(G + (size_t)(rb + s_row0) * K_DIM + kb + s_col0,
            lbase + blkB + (wave << 10));
    gload16(G + (size_t)(rb + s_row1) * K_DIM + kb + s_col1,
            lbase + blkB + 8192 + (wave << 10));
  };

  f32x16 acc[4][2];
#pragma unroll
  for (int i = 0; i < 4; ++i)
#pragma unroll
    for (int j = 0; j < 2; ++j)
      acc[i][j] = (f32x16)(0.f);

  // Prologue: T0 all 4 blocks + T1 slice-0 blocks
  STAGE(A, row0, 0,  0);
  STAGE(W, col0, 0,  32768);
  STAGE(A, row0, 32, 16384);
  STAGE(W, col0, 32, 49152);
  STAGE(A, row0, 64, 65536);
  STAGE(W, col0, 64, 98304);
  asm volatile("s_waitcnt vmcnt(4)" ::: "memory");  // T0 resident, T1-s0 in flight
  __builtin_amdgcn_s_barrier();

  bf16x8 a[2][2], b[2][2];  // [frag][k-granule]

  // A frag addr: slice + ((wm*128 + mi*32 + r32) * 64) + g*32 + hk, swizzled
#define ARD(sliceB, mi, g) \
  (*(const bf16x8*)(lbase + (sliceB) + SWZ((((wm * 128 + (mi) * 32 + r32)) << 6) + (g) * 32 + hk)))
#define BRD(sliceB, ni, g) \
  (*(const bf16x8*)(lbase + (sliceB) + SWZ((((wn * 64 + (ni) * 32 + r32)) << 6) + (g) * 32 + hk)))

  for (int t = 0; t < 64; ++t) {
    const int cur  = t & 1;
    const int curB = cur << 16;
    const int nxtB = (cur ^ 1) << 16;
    const int t1   = (t + 1 < 64) ? t + 1 : 63;  // clamp keeps vmcnt uniform
    const int t2   = (t + 2 < 64) ? t + 2 : 63;

    // ---- P1: ks0 x m-half0 ----
#pragma unroll
    for (int mi = 0; mi < 2; ++mi)
#pragma unroll
      for (int g = 0; g < 2; ++g) a[mi][g] = ARD(curB, mi, g);
#pragma unroll
    for (int ni = 0; ni < 2; ++ni)
#pragma unroll
      for (int g = 0; g < 2; ++g) b[ni][g] = BRD(curB + 32768, ni, g);
    STAGE(A, row0, t1 * 64 + 32, nxtB + 16384);  // T(t+1) A s1
    __builtin_amdgcn_s_barrier();
    asm volatile("s_waitcnt lgkmcnt(0)" ::: "memory");
    __builtin_amdgcn_s_setprio(1);
#pragma unroll
    for (int g = 0; g < 2; ++g)
#pragma unroll
      for (int mi = 0; mi < 2; ++mi)
#pragma unroll
        for (int ni = 0; ni < 2; ++ni)
          acc[mi][ni] = MFMA32(a[mi][g], b[ni][g], acc[mi][ni]);
    __builtin_amdgcn_s_setprio(0);
    __builtin_amdgcn_s_barrier();

    // ---- P2: ks0 x m-half1 (reuse b) ----
#pragma unroll
    for (int mi = 0; mi < 2; ++mi)
#pragma unroll
      for (int g = 0; g < 2; ++g) a[mi][g] = ARD(curB, 2 + mi, g);
    STAGE(W, col0, t1 * 64 + 32, nxtB + 49152);  // T(t+1) B s1
    __builtin_amdgcn_s_barrier();
    asm volatile("s_waitcnt lgkmcnt(0)" ::: "memory");
    __builtin_amdgcn_s_setprio(1);
#pragma unroll
    for (int g = 0; g < 2; ++g)
#pragma unroll
      for (int mi = 0; mi < 2; ++mi)
#pragma unroll
        for (int ni = 0; ni < 2; ++ni)
          acc[2 + mi][ni] = MFMA32(a[mi][g], b[ni][g], acc[2 + mi][ni]);
    __builtin_amdgcn_s_setprio(0);
    __builtin_amdgcn_s_barrier();

    // ---- P3: ks1 x m-half0 ----
#pragma unroll
    for (int mi = 0; mi < 2; ++mi)
#pragma unroll
      for (int g = 0; g < 2; ++g) a[mi][g] = ARD(curB + 16384, mi, g);
#pragma unroll
    for (int ni = 0; ni < 2; ++ni)
#pragma unroll
      for (int g = 0; g < 2; ++g) b[ni][g] = BRD(curB + 49152, ni, g);
    STAGE(A, row0, t2 * 64, curB);  // T(t+2) A s0 -> dead region
    __builtin_amdgcn_s_barrier();
    asm volatile("s_waitcnt lgkmcnt(0)" ::: "memory");
    __builtin_amdgcn_s_setprio(1);
#pragma unroll
    for (int g = 0; g < 2; ++g)
#pragma unroll
      for (int mi = 0; mi < 2; ++mi)
#pragma unroll
        for (int ni = 0; ni < 2; ++ni)
          acc[mi][ni] = MFMA32(a[mi][g], b[ni][g], acc[mi][ni]);
    __builtin_amdgcn_s_setprio(0);
    __builtin_amdgcn_s_barrier();

    // ---- P4: ks1 x m-half1 (reuse b) ----
#pragma unroll
    for (int mi = 0; mi < 2; ++mi)
#pragma unroll
      for (int g = 0; g < 2; ++g) a[mi][g] = ARD(curB + 16384, 2 + mi, g);
    STAGE(W, col0, t2 * 64, curB + 32768);  // T(t+2) B s0 -> dead region
    __builtin_amdgcn_s_barrier();
    asm volatile("s_waitcnt lgkmcnt(0)" ::: "memory");
    __builtin_amdgcn_s_setprio(1);
#pragma unroll
    for (int g = 0; g < 2; ++g)
#pragma unroll
      for (int mi = 0; mi < 2; ++mi)
#pragma unroll
        for (int ni = 0; ni < 2; ++ni)
          acc[2 + mi][ni] = MFMA32(a[mi][g], b[ni][g], acc[2 + mi][ni]);
    __builtin_amdgcn_s_setprio(0);
    // counted wait: <=4 outstanding (= T(t+2) s0); T(t+1) s1 fully landed
    asm volatile("s_waitcnt vmcnt(4)" ::: "memory");
    __builtin_amdgcn_s_barrier();
  }

  // don't retire with in-flight LDS writes
  asm volatile("s_waitcnt vmcnt(0)" ::: "memory");

  // Epilogue: 32x32 C/D layout col=lane&31, row=(reg&3)+8*(reg>>2)+4*(lane>>5)
  const int h4 = (lane >> 5) * 4;
#pragma unroll
  for (int ni = 0; ni < 2; ++ni) {
    const int col = col0 + wn * 64 + ni * 32 + r32;
    const float sc = scale[col];
    const float bv = bias[col];
#pragma unroll
    for (int mi = 0; mi < 4; ++mi) {
      const int rowb = row0 + wm * 128 + mi * 32 + h4;
#pragma unroll
      for (int reg = 0; reg < 16; ++reg) {
        const int row = rowb + (reg & 3) + 8 * (reg >> 2);
        C[(size_t)row * N_DIM + col] = acc[mi][ni][reg] * sc + bv;
      }
    }
  }
}

extern "C" void kernel_launch(void* const* d_in, const int* in_sizes, int n_in,
                              void* d_out, int out_size, void* d_ws, size_t ws_size,
                              hipStream_t stream) {
  const float* x      = (const float*)d_in[0];
  const int*   wq     = (const int*)d_in[1];
  const float* wscale = (const float*)d_in[2];
  const float* wbias  = (const float*)d_in[3];
  float* out = (float*)d_out;

  const size_t xb_bytes = (size_t)M_TOT * K_DIM * 2;   // 32 MB
  const size_t wb_bytes = (size_t)N_DIM * K_DIM * 2;   // 128 MB
  if (ws_size < xb_bytes + wb_bytes) return;

  ushort* xb = (ushort*)d_ws;
  ushort* wb = (ushort*)((char*)d_ws + xb_bytes);

  cvt_f32_bf16_k<<<2048, 256, 0, stream>>>((const float4*)x, (ushort4*)xb,
                                           (M_TOT * K_DIM) / 4);
  cvt_i32_bf16_k<<<2048, 256, 0, stream>>>((const int4*)wq, (ushort4*)wb,
                                           (N_DIM * K_DIM) / 4);

  const int grid = (M_TOT / 256) * (N_DIM / 256);  // 16 * 64 = 1024
  gemm_8phase<<<grid, 512, 0, stream>>>(xb, wb, wscale, wbias, out);
}